// Round 9
// baseline (1751.046 us; speedup 1.0000x reference)
//
#include <hip/hip_runtime.h>

#define TT 365
#define BB 512
#define DD 16
#define HH 256
#define SS 32

typedef __attribute__((ext_vector_type(8))) short short8;
typedef __attribute__((ext_vector_type(4))) float f32x4;
typedef __attribute__((ext_vector_type(4))) unsigned u32x4;
typedef unsigned long long u64;

// Ring poison: tag bits (14,30) set in both dwords = tag-code 3; first poll of
// any address wants code 0..2 before 3 can recur => never false-match.
#define SENT 0x7FC07FC07FC07FC0ULL
// 2-bit generation tag per dword: bit14 (low bf16) + bit30 (high bf16).
// |h|<=1 => biased exp <= 127 => both bits are 0 in any published bf16.
#define TMASK64 0x4000400040004000ULL

__device__ __host__ inline short f2bf(float f){
  union { float f; unsigned u; } v; v.f = f;
  unsigned r = v.u + 0x7FFFu + ((v.u >> 16) & 1u);
  return (short)(r >> 16);
}
__device__ inline float sigm(float x){ return 1.0f/(1.0f+__expf(-x)); }
__device__ inline float tanhx(float x){ return 2.0f/(1.0f+__expf(-2.0f*x)) - 1.0f; }

// RNE f32x2 -> packed bf16x2 (same rounding as f2bf; h is never NaN)
__device__ inline unsigned cvtpk(float a, float b){
  unsigned r;
  asm("v_cvt_pk_bf16_f32 %0, %1, %2" : "=v"(r) : "v"(a), "v"(b));
  return r;
}

// A-fragment address (shorts) in an 8KB K=256 region for mfma_16x16x32 A-layout.
__device__ inline int fragAddr(int k, int m){
  return ((k>>5)*512) + ((((k&31)>>3)*16 + m)*8) + (k&7);
}

// Coherence-point store (HW-verified visible to sc0+sc1 polls, R2..R8).
__device__ inline void pub_store(u64* p, u64 v){
  asm volatile("global_store_dwordx2 %0, %1, off sc0 sc1"
               :: "v"(p), "v"(v) : "memory");
}

// Raw barrier: LDS-drain only; publish stores / polls / atomics stay in flight.
#define RAW_BAR() do{ \
    asm volatile("s_waitcnt lgkmcnt(0)\n\ts_barrier" ::: "memory"); \
    __builtin_amdgcn_sched_barrier(0); }while(0)

// One 16B tagged-poll load per partner ({h0,h1} packet), 3 partners.
#define ISSUE3(o0,o1,o2,a0,a1,a2) \
  asm volatile( \
    "global_load_dwordx4 %0, %3, off sc0 sc1\n\t" \
    "global_load_dwordx4 %1, %4, off sc0 sc1\n\t" \
    "global_load_dwordx4 %2, %5, off sc0 sc1" \
    : "=&v"(o0),"=&v"(o1),"=&v"(o2) \
    : "v"(a0),"v"(a1),"v"(a2) : "memory")

// ---------------- prep kernels ----------------
__global__ void prep_weights(const float* __restrict__ Wih0, const float* __restrict__ Whh0,
                             const float* __restrict__ Wih1, const float* __restrict__ Whh1,
                             short* __restrict__ Wb0, short* __restrict__ Wb1)
{
  int idx = blockIdx.x*blockDim.x + threadIdx.x;
  const int n0 = 16*36*512;
  const int n1 = 16*64*512;
  if (idx < n0){
    int frag = idx >> 9, pos = idx & 511;
    int lane = pos >> 3, jj = pos & 7;
    int slot = frag / 36, rem = frag % 36;
    int ks = rem >> 2, nt = rem & 3;
    int n = nt*256 + slot*16 + (lane & 15);
    float v = 0.0f;
    if (ks == 0){
      int k32 = (lane>>4)*8 + jj;
      if (k32 < 16) v = Wih0[n*16 + k32];
    } else {
      int k = (ks-1)*32 + (lane>>4)*8 + jj;
      v = Whh0[n*256 + k];
    }
    Wb0[idx] = f2bf(v);
  } else if (idx < n0 + n1){
    int e = idx - n0;
    int frag = e >> 9, pos = e & 511;
    int lane = pos >> 3, jj = pos & 7;
    int slot = frag >> 6, rem = frag & 63;
    int ks = rem >> 2, nt = rem & 3;
    int n = nt*256 + slot*16 + (lane & 15);
    int k = ks*32 + (lane>>4)*8 + jj;
    float v = (k < 256) ? Wih1[n*256 + k] : Whh1[n*256 + (k-256)];
    Wb1[e] = f2bf(v);
  }
}

__global__ void prep_h0(const float* __restrict__ xs, const float* __restrict__ Ws,
                        const float* __restrict__ bs, float* __restrict__ h0init)
{
  int i = blockIdx.x*blockDim.x + threadIdx.x;
  int b = i >> 8, jj = i & 255;
  float s = bs[jj];
  const float* xr = xs + b*SS;
  const float* wr = Ws + jj*SS;
#pragma unroll
  for (int q=0;q<SS;++q) s += xr[q]*wr[q];
  h0init[i] = s;
}

__global__ void prep_bias(const float* __restrict__ a0, const float* __restrict__ a1,
                          const float* __restrict__ a2, const float* __restrict__ a3,
                          float* __restrict__ b0o, float* __restrict__ b1o)
{
  int i = threadIdx.x + blockIdx.x*blockDim.x;
  if (i < 1024) b0o[i] = a0[i] + a1[i];
  else if (i < 2048) b1o[i-1024] = a2[i-1024] + a3[i-1024];
}

__global__ void prep_zero(float* __restrict__ out, u64* __restrict__ ring)
{
  int i = blockIdx.x*blockDim.x + threadIdx.x;
  if (i < BB*TT) out[i] = 0.0f;
  if (i < 131072) ring[i] = SENT;   // 2 slots x 32 g x 2048 u64 = 1MB
}

// ---------------- persistent fused LSTM ----------------
// 128 blocks x 256 threads; g = bid&31 (16 batch rows), c = bid>>5 (64 hidden cols).
// Weights register/AGPR-resident. Lag pipeline: superstep s runs L0@t=s, L1@t=s-1.
//
// SINGLE-EXCHANGE schedule (R9): everything a consumer needs at step s —
// partner h0(s-1) AND h1(s-2) — was published during partner step s-1, as one
// packet {h0,h1} in adjacent u64s (slot (s-1)&1, 2-bit tag T=((s-1)>>1)&3 in
// bit14+bit30 of every dword; period-8, skew<=1 via mutual consumption => no ABA;
// publish-before-poll per step => no deadlock).
//
// Per step: B0 | issue 3x dwordx4 polls + xf | w1 out-flush(t=s-2) | own-frag
// stage (regs->LDS) | ONE counted check | scatter partner frags | AX | B1 |
// L1 (64 MFMA) -> epi -> pub h1(s-1) | L0 (36 MFMA) -> epi -> pub h0(s) |
// reduce -> outacc. MFMA phase is an uninterrupted burst; AH0/AH1 single-buffered
// (stage/read split by B1, reuse split by B0). ALL loop VMEM is inline asm.
// vmcnt streams (in-order retire): steady [pubH1,pubH0, p x3, xf(, atomic w1)]
//  -> check vmcnt(1) (w1: vmcnt(2)); AX-stage vmcnt(0) (w1: vmcnt(1)).
__global__ __launch_bounds__(256, 1) void lstm_fused(
    const short* __restrict__ Wb0, const short* __restrict__ Wb1,
    const float* __restrict__ h0i, const float* __restrict__ b0c,
    const float* __restrict__ b1c, const float* __restrict__ x,
    const float* __restrict__ Wo, const float* __restrict__ bo,
    u64* __restrict__ ring, float* __restrict__ out)
{
  __shared__ alignas(16) short AX[512];
  __shared__ alignas(16) short AH0[4096];
  __shared__ alignas(16) short AH1[4096];
  __shared__ float outacc[2][16][4];

  const int tid  = threadIdx.x;
  const int w    = tid >> 6;
  const int lane = tid & 63;
  const int col16= lane & 15;
  const int quad = lane >> 4;
  const int c    = blockIdx.x >> 5;
  const int g    = blockIdx.x & 31;
  const int rowbase = g * 16;
  const int slot = c*4 + w;
  const int colg = slot*16 + col16;

  // ---- register-resident weight fragments ----
  short8 F0[36], F1[64];
  {
    const short8* p0 = (const short8*)Wb0 + slot*36*64 + lane;
#pragma unroll
    for (int f=0; f<36; ++f) F0[f] = p0[f*64];
    const short8* p1 = (const short8*)Wb1 + slot*64*64 + lane;
#pragma unroll
    for (int f=0; f<64; ++f) F1[f] = p1[f*64];
  }
  float bia0[4], bia1[4];
#pragma unroll
  for (int nt=0; nt<4; ++nt){
    bia0[nt] = b0c[nt*256 + slot*16 + col16];
    bia1[nt] = b1c[nt*256 + slot*16 + col16];
  }
  const float wo = Wo[colg];
  const float bos = bo[0];

  // ---- init ----
  float c0[4], c1[4];
#pragma unroll
  for (int r=0; r<4; ++r){
    c0[r] = h0i[(rowbase + quad*4 + r)*HH + colg];
    c1[r] = c0[r];
  }
  for (int i = tid; i < 4096; i += 256){
    int m = i >> 8, k = i & 255;
    short v = f2bf(h0i[(rowbase+m)*HH + k]);
    int a = fragAddr(k,m);
    AH0[a] = v;      // h0(-1) = h0init
    AH1[a] = v;      // h1(-1) = h0init (used at s==1)
  }
  {
    int m = tid >> 4, d = tid & 15;
    AX[fragAddr(16 + d, m)] = 0;   // K-pad stays zero forever
  }
  __syncthreads();   // clean vmcnt/lgkm slate entering the loop

  const f32x4 zero = {0.0f,0.0f,0.0f,0.0f};
  const int qd = tid & 3;
  const int cl = (tid >> 2) & 63;
  const int ka = (((c + 1) & 3) << 6) + cl;
  const int kb = (((c + 2) & 3) << 6) + cl;
  const int kc = (((c + 3) & 3) << 6) + cl;

  u64 pv0_prev = 0, pv1_prev = 0;

#define CHKH(lo64,dst,fl,TG) do{ u64 _t=(lo64); \
    if(!(fl) && ((_t & TMASK64)==(TG))){ (dst)=_t & ~TMASK64; (fl)=true; } }while(0)

  for (int s=0; s<=TT; ++s){
    const bool doL0   = (s < TT);
    const bool doL1   = (s >= 1);
    const bool doPoll = (s >= 1);
    const bool doH1   = (s >= 2);     // h1-half valid; AH1 restage
    const bool doFl   = (s >= 2);     // out-flush t=s-2
    const int  p  = s & 1;
    const unsigned T0 = (s>>1)&3;
    const unsigned w0_32 = ((T0&1)?0x4000u:0u) | ((T0&2)?0x40000000u:0u);
    const u64 tg0 = ((u64)w0_32<<32)|w0_32;            // my publish tag
    const unsigned Tp = ((s-1)>>1)&3;
    const unsigned wp_32 = ((Tp&1)?0x4000u:0u) | ((Tp&2)?0x40000000u:0u);
    const u64 tgp = ((u64)wp_32<<32)|wp_32;            // polled tag (step s-1)

    u64* rbMe = ring + (u64)(p*32+g)*2048;
    u64* rbP  = ring + (u64)(((s-1)&1)*32+g)*2048;
    const u64* Pa = rbP + (ka*4+qd)*2;
    const u64* Pb = rbP + (kb*4+qd)*2;
    const u64* Pc = rbP + (kc*4+qd)*2;

    RAW_BAR();  // B0: prev compute's LDS reads done; stage may overwrite

    // issue polls (oldest new ops) then xf, then w1's atomic (newest)
    u32x4 ea, eb, ec;
    if (doPoll){ ISSUE3(ea, eb, ec, Pa, Pb, Pc); }
    float xf = 0.0f;
    if (doL0){
      const float* xp = x + (rowbase+(tid>>4))*TT*DD + s*DD + (tid&15);
      asm volatile("global_load_dword %0, %1, off" : "=&v"(xf) : "v"(xp) : "memory");
    }
    if (doFl && tid >= 64 && tid < 80){
      int row = tid - 64;
      float v = outacc[p^1][row][0] + outacc[p^1][row][1]
              + outacc[p^1][row][2] + outacc[p^1][row][3];
      if (c == 0) v += bos;
      atomicAdd(&out[(rowbase + row)*TT + (s-2)], v);
    }

    // own frags from registers (overlap poll RTT)
    if (doPoll){
#pragma unroll
      for (int r=0; r<4; ++r)
        AH0[fragAddr(colg, quad*4 + r)] = (short)(pv0_prev >> (16*r));
    }
    if (doH1){
#pragma unroll
      for (int r=0; r<4; ++r)
        AH1[fragAddr(colg, quad*4 + r)] = (short)(pv1_prev >> (16*r));
    }

    // ---- the ONE check ----
    if (doPoll){
      const int extra = (doL0 ? 1 : 0) + ((doFl && w == 1) ? 1 : 0);
      __builtin_amdgcn_sched_barrier(0);
      if (extra == 2)      asm volatile("s_waitcnt vmcnt(2)" ::: "memory");
      else if (extra == 1) asm volatile("s_waitcnt vmcnt(1)" ::: "memory");
      else                 asm volatile("s_waitcnt vmcnt(0)" ::: "memory");
      __builtin_amdgcn_sched_barrier(0);
      u64 h0a=0,h0b=0,h0c=0,h1a=0,h1b=0,h1c=0;
      bool f0a=false,f0b=false,f0c=false;
      bool f1a=!doH1, f1b=!doH1, f1c=!doH1;
      CHKH((((u64)ea.y)<<32)|ea.x, h0a, f0a, tgp);
      CHKH((((u64)ea.w)<<32)|ea.z, h1a, f1a, tgp);
      CHKH((((u64)eb.y)<<32)|eb.x, h0b, f0b, tgp);
      CHKH((((u64)eb.w)<<32)|eb.z, h1b, f1b, tgp);
      CHKH((((u64)ec.y)<<32)|ec.x, h0c, f0c, tgp);
      CHKH((((u64)ec.w)<<32)|ec.z, h1c, f1c, tgp);
      while (!(f0a & f0b & f0c & f1a & f1b & f1c)){
        ISSUE3(ea, eb, ec, Pa, Pb, Pc);
        asm volatile("s_waitcnt vmcnt(0)" ::: "memory");
        __builtin_amdgcn_sched_barrier(0);
        CHKH((((u64)ea.y)<<32)|ea.x, h0a, f0a, tgp);
        CHKH((((u64)ea.w)<<32)|ea.z, h1a, f1a, tgp);
        CHKH((((u64)eb.y)<<32)|eb.x, h0b, f0b, tgp);
        CHKH((((u64)eb.w)<<32)|eb.z, h1b, f1b, tgp);
        CHKH((((u64)ec.y)<<32)|ec.x, h0c, f0c, tgp);
        CHKH((((u64)ec.w)<<32)|ec.z, h1c, f1c, tgp);
      }
      // scatter partner frags
      {
        short* sv = (short*)&h0a;
#pragma unroll
        for (int r=0; r<4; ++r) AH0[fragAddr(ka, qd*4 + r)] = sv[r];
        sv = (short*)&h0b;
#pragma unroll
        for (int r=0; r<4; ++r) AH0[fragAddr(kb, qd*4 + r)] = sv[r];
        sv = (short*)&h0c;
#pragma unroll
        for (int r=0; r<4; ++r) AH0[fragAddr(kc, qd*4 + r)] = sv[r];
      }
      if (doH1){
        short* sw = (short*)&h1a;
#pragma unroll
        for (int r=0; r<4; ++r) AH1[fragAddr(ka, qd*4 + r)] = sw[r];
        sw = (short*)&h1b;
#pragma unroll
        for (int r=0; r<4; ++r) AH1[fragAddr(kb, qd*4 + r)] = sw[r];
        sw = (short*)&h1c;
#pragma unroll
        for (int r=0; r<4; ++r) AH1[fragAddr(kc, qd*4 + r)] = sw[r];
      }
    }

    // AX stage (xf retired; leave w1's atomic in flight)
    if (doL0){
      __builtin_amdgcn_sched_barrier(0);
      if (doFl && w == 1) asm volatile("s_waitcnt vmcnt(1)" ::: "memory");
      else                asm volatile("s_waitcnt vmcnt(0)" ::: "memory");
      __builtin_amdgcn_sched_barrier(0);
      AX[fragAddr(tid & 15, tid >> 4)] = f2bf(xf);
    }

    RAW_BAR();  // B1: all frags staged; compute may read

    // ---- L1 first: 64 MFMA -> epi -> publish h1(s-1) EARLY ----
    u64 pv1 = 0;
    float pr[4];
    if (doL1){
      f32x4 acc1[4];
#pragma unroll
      for (int nt=0; nt<4; ++nt) acc1[nt] = zero;
#pragma unroll
      for (int ks=0; ks<8; ++ks){
        short8 a = *(const short8*)(AH0 + ks*512 + lane*8);
#pragma unroll
        for (int nt=0; nt<4; ++nt)
          acc1[nt] = __builtin_amdgcn_mfma_f32_16x16x32_bf16(a, F1[ks*4+nt], acc1[nt], 0,0,0);
      }
#pragma unroll
      for (int ks=0; ks<8; ++ks){
        short8 a = *(const short8*)(AH1 + ks*512 + lane*8);
#pragma unroll
        for (int nt=0; nt<4; ++nt)
          acc1[nt] = __builtin_amdgcn_mfma_f32_16x16x32_bf16(a, F1[32+ks*4+nt], acc1[nt], 0,0,0);
      }
      float h1v[4];
#pragma unroll
      for (int r=0; r<4; ++r){
        float iv = sigm (acc1[0][r] + bia1[0]);
        float fv = sigm (acc1[1][r] + bia1[1]);
        float gv = tanhx(acc1[2][r] + bia1[2]);
        float ov = sigm (acc1[3][r] + bia1[3]);
        float cc = fv*c1[r] + iv*gv;
        c1[r] = cc;
        float h = ov * tanhx(cc);
        h1v[r] = h;
        pr[r] = h * wo;
      }
      pv1 = (((u64)cvtpk(h1v[2], h1v[3])) << 32) | cvtpk(h1v[0], h1v[1]);
      if (s < TT)
        pub_store(rbMe + (colg*4+quad)*2 + 1, pv1 | tg0);
    }

    // ---- L0: 36 MFMA -> epi -> publish h0(s) ----
    u64 pv0 = 0;
    if (doL0){
      f32x4 acc0[4];
#pragma unroll
      for (int nt=0; nt<4; ++nt) acc0[nt] = zero;
      {
        short8 a = *(const short8*)(AX + lane*8);
#pragma unroll
        for (int nt=0; nt<4; ++nt)
          acc0[nt] = __builtin_amdgcn_mfma_f32_16x16x32_bf16(a, F0[nt], acc0[nt], 0,0,0);
      }
#pragma unroll
      for (int ks=0; ks<8; ++ks){
        short8 a = *(const short8*)(AH0 + ks*512 + lane*8);
#pragma unroll
        for (int nt=0; nt<4; ++nt)
          acc0[nt] = __builtin_amdgcn_mfma_f32_16x16x32_bf16(a, F0[(ks+1)*4+nt], acc0[nt], 0,0,0);
      }
      float h0v[4];
#pragma unroll
      for (int r=0; r<4; ++r){
        float iv = sigm (acc0[0][r] + bia0[0]);
        float fv = sigm (acc0[1][r] + bia0[1]);
        float gv = tanhx(acc0[2][r] + bia0[2]);
        float ov = sigm (acc0[3][r] + bia0[3]);
        float cc = fv*c0[r] + iv*gv;
        c0[r] = cc;
        h0v[r] = ov * tanhx(cc);
      }
      pv0 = (((u64)cvtpk(h0v[2], h0v[3])) << 32) | cvtpk(h0v[0], h0v[1]);
      pub_store(rbMe + (colg*4+quad)*2, pv0 | tg0);
    }

    // ---- reduce AFTER pub-h0 (ages the publish before next step's polls) ----
    if (doL1){
#pragma unroll
      for (int m=1; m<16; m<<=1){
#pragma unroll
        for (int r=0; r<4; ++r) pr[r] += __shfl_xor(pr[r], m, 64);
      }
      if (col16 == 0){
#pragma unroll
        for (int r=0; r<4; ++r) outacc[p][quad*4 + r][w] = pr[r];
      }
    }

    pv0_prev = pv0;
    pv1_prev = pv1;
  }
#undef CHKH

  // ---- final flush: t = TT-1 lives in outacc[TT&1] ----
  RAW_BAR();
  if (tid < 16){
    const int pf = TT & 1;
    float v = outacc[pf][tid][0] + outacc[pf][tid][1]
            + outacc[pf][tid][2] + outacc[pf][tid][3];
    if (c == 0) v += bos;
    atomicAdd(&out[(rowbase + tid)*TT + (TT-1)], v);
  }
}

// ---------------- launch ----------------
extern "C" void kernel_launch(void* const* d_in, const int* in_sizes, int n_in,
                              void* d_out, int out_size, void* d_ws, size_t ws_size,
                              hipStream_t stream)
{
  const float* x    = (const float*)d_in[0];
  const float* xs   = (const float*)d_in[1];
  const float* Wih0 = (const float*)d_in[2];
  const float* Whh0 = (const float*)d_in[3];
  const float* bih0 = (const float*)d_in[4];
  const float* bhh0 = (const float*)d_in[5];
  const float* Wih1 = (const float*)d_in[6];
  const float* Whh1 = (const float*)d_in[7];
  const float* bih1 = (const float*)d_in[8];
  const float* bhh1 = (const float*)d_in[9];
  const float* Ws   = (const float*)d_in[10];
  const float* bs   = (const float*)d_in[11];
  const float* Wo   = (const float*)d_in[12];
  const float* bo   = (const float*)d_in[13];
  float* out = (float*)d_out;

  char* ws = (char*)d_ws;
  short*    Wb0   = (short*)(ws);                // 589824
  short*    Wb1   = (short*)(ws + 589824);       // 1048576 -> 1638400
  float*    h0i   = (float*)(ws + 1638400);      // 524288  -> 2162688
  float*    b0cp  = (float*)(ws + 2162688);      // 4096    -> 2166784
  float*    b1cp  = (float*)(ws + 2166784);      // 4096    -> 2170880
  u64*      ring  = (u64*)(ws + 2170880);        // 1048576 -> 3219456 (~3.22 MB)

  int nswz = 16*36*512 + 16*64*512;
  hipLaunchKernelGGL(prep_weights, dim3((nswz+255)/256), dim3(256), 0, stream,
                     Wih0, Whh0, Wih1, Whh1, Wb0, Wb1);
  hipLaunchKernelGGL(prep_h0, dim3(512), dim3(256), 0, stream, xs, Ws, bs, h0i);
  hipLaunchKernelGGL(prep_bias, dim3(8), dim3(256), 0, stream, bih0, bhh0, bih1, bhh1, b0cp, b1cp);
  hipLaunchKernelGGL(prep_zero, dim3(1024), dim3(256), 0, stream, out, ring);

  hipLaunchKernelGGL(lstm_fused, dim3(128), dim3(256), 0, stream,
                     Wb0, Wb1, h0i, b0cp, b1cp, x, Wo, bo, ring, out);
}

// Round 10
// 1629.053 us; speedup vs baseline: 1.0749x; 1.0749x over previous
//
#include <hip/hip_runtime.h>

#define TT 365
#define BB 512
#define DD 16
#define HH 256
#define SS 32

typedef __attribute__((ext_vector_type(8))) short short8;
typedef __attribute__((ext_vector_type(4))) float f32x4;
typedef unsigned long long u64;

// Ring poison: tag bits (14,30) set in both dwords = tag-code 3.
#define SENT 0x7FC07FC07FC07FC0ULL
// 2-bit generation tag per dword: bit14 (low bf16) + bit30 (high bf16).
// |h|<=1 => biased exp <= 127 => both bits are 0 in any published bf16.
#define TMASK64 0x4000400040004000ULL

__device__ __host__ inline short f2bf(float f){
  union { float f; unsigned u; } v; v.f = f;
  unsigned r = v.u + 0x7FFFu + ((v.u >> 16) & 1u);
  return (short)(r >> 16);
}
__device__ inline float sigm(float x){ return 1.0f/(1.0f+__expf(-x)); }
__device__ inline float tanhx(float x){ return 2.0f/(1.0f+__expf(-2.0f*x)) - 1.0f; }

// RNE f32x2 -> packed bf16x2 (same rounding as f2bf; h is never NaN)
__device__ inline unsigned cvtpk(float a, float b){
  unsigned r;
  asm("v_cvt_pk_bf16_f32 %0, %1, %2" : "=v"(r) : "v"(a), "v"(b));
  return r;
}

// A-fragment address (shorts) in an 8KB K=256 region for mfma_16x16x32 A-layout.
__device__ inline int fragAddr(int k, int m){
  return ((k>>5)*512) + ((((k&31)>>3)*16 + m)*8) + (k&7);
}

// Coherence-point store (HW-verified visible to sc0+sc1 polls, R2..R8).
__device__ inline void pub_store(u64* p, u64 v){
  asm volatile("global_store_dwordx2 %0, %1, off sc0 sc1"
               :: "v"(p), "v"(v) : "memory");
}

// Raw barrier: LDS-drain only; publish stores / polls / atomics stay in flight.
#define RAW_BAR() do{ \
    asm volatile("s_waitcnt lgkmcnt(0)\n\ts_barrier" ::: "memory"); \
    __builtin_amdgcn_sched_barrier(0); }while(0)

// ---------------- prep kernels ----------------
__global__ void prep_weights(const float* __restrict__ Wih0, const float* __restrict__ Whh0,
                             const float* __restrict__ Wih1, const float* __restrict__ Whh1,
                             short* __restrict__ Wb0, short* __restrict__ Wb1)
{
  int idx = blockIdx.x*blockDim.x + threadIdx.x;
  const int n0 = 16*36*512;
  const int n1 = 16*64*512;
  if (idx < n0){
    int frag = idx >> 9, pos = idx & 511;
    int lane = pos >> 3, jj = pos & 7;
    int slot = frag / 36, rem = frag % 36;
    int ks = rem >> 2, nt = rem & 3;
    int n = nt*256 + slot*16 + (lane & 15);
    float v = 0.0f;
    if (ks == 0){
      int k32 = (lane>>4)*8 + jj;
      if (k32 < 16) v = Wih0[n*16 + k32];
    } else {
      int k = (ks-1)*32 + (lane>>4)*8 + jj;
      v = Whh0[n*256 + k];
    }
    Wb0[idx] = f2bf(v);
  } else if (idx < n0 + n1){
    int e = idx - n0;
    int frag = e >> 9, pos = e & 511;
    int lane = pos >> 3, jj = pos & 7;
    int slot = frag >> 6, rem = frag & 63;
    int ks = rem >> 2, nt = rem & 3;
    int n = nt*256 + slot*16 + (lane & 15);
    int k = ks*32 + (lane>>4)*8 + jj;
    float v = (k < 256) ? Wih1[n*256 + k] : Whh1[n*256 + (k-256)];
    Wb1[e] = f2bf(v);
  }
}

__global__ void prep_h0(const float* __restrict__ xs, const float* __restrict__ Ws,
                        const float* __restrict__ bs, float* __restrict__ h0init)
{
  int i = blockIdx.x*blockDim.x + threadIdx.x;
  int b = i >> 8, jj = i & 255;
  float s = bs[jj];
  const float* xr = xs + b*SS;
  const float* wr = Ws + jj*SS;
#pragma unroll
  for (int q=0;q<SS;++q) s += xr[q]*wr[q];
  h0init[i] = s;
}

__global__ void prep_bias(const float* __restrict__ a0, const float* __restrict__ a1,
                          const float* __restrict__ a2, const float* __restrict__ a3,
                          float* __restrict__ b0o, float* __restrict__ b1o)
{
  int i = threadIdx.x + blockIdx.x*blockDim.x;
  if (i < 1024) b0o[i] = a0[i] + a1[i];
  else if (i < 2048) b1o[i-1024] = a2[i-1024] + a3[i-1024];
}

__global__ void prep_zero(float* __restrict__ out, u64* __restrict__ ring)
{
  int i = blockIdx.x*blockDim.x + threadIdx.x;
  if (i < BB*TT) out[i] = 0.0f;
  if (i < 131072) ring[i] = SENT;   // 2 slots x 32 g x 2048 u64 = 1MB
}

// ---------------- persistent fused LSTM ----------------
// 128 blocks x 256 threads; g = bid&31 (16 batch rows), c = bid>>5 (64 hidden cols).
// Weights register/AGPR-resident. Lag pipeline: superstep s runs L0@t=s, L1@t=s-1.
//
// Exchange: generation-tagged packets {h0(s), h1(s-1)}, slot s&1, 2-BIT tag
// T=(s>>1)&3 in (bit14,bit30) of every dword (Delta-s=8 to collide; skew<=1 via
// mutual consumption => no ABA). Read-only sc0+sc1 polls; no atomics in exchange.
//
// R10 = R8 with a serial-chain diet:
//  B0 | w1 out-flush | issue h1(s-2) polls | xf asm load
//  L0: 36 MFMA -> epi -> pub h0(s) -> own h0 frags -> ISSUE h0(s) polls
//      (0.27P: window ~0.53P to the tail check)
//  L1a: 32 MFMA (Wih1 x AH0)    [uninterrupted]
//  h1-check vmcnt(5) -> fill AH1 (partners + own pv1_prev)
//  B1 | L1b: 32 MFMA -> epi -> pub h1(s-1) -> reduce -> outacc[p]
//  tail: ONE gate vmcnt(1) -> AX stage + h0-check + partner frags
// Only post-wait sched_barriers kept (rule-18 minimum); "memory" clobber
// anchors ds_reads around the waits. Stream (s>=2, after B0):
// [h1p x3, xf, pubH0, h0p x3, pubH1] (+atomic oldest on wave1).
__global__ __launch_bounds__(256, 1) void lstm_fused(
    const short* __restrict__ Wb0, const short* __restrict__ Wb1,
    const float* __restrict__ h0i, const float* __restrict__ b0c,
    const float* __restrict__ b1c, const float* __restrict__ x,
    const float* __restrict__ Wo, const float* __restrict__ bo,
    u64* __restrict__ ring, float* __restrict__ out)
{
  __shared__ alignas(16) short AX[2][512];
  __shared__ alignas(16) short AH0[2][4096];
  __shared__ alignas(16) short AH1[4096];
  __shared__ float outacc[2][16][4];

  const int tid  = threadIdx.x;
  const int w    = tid >> 6;
  const int lane = tid & 63;
  const int col16= lane & 15;
  const int quad = lane >> 4;
  const int c    = blockIdx.x >> 5;
  const int g    = blockIdx.x & 31;
  const int rowbase = g * 16;
  const int slot = c*4 + w;
  const int colg = slot*16 + col16;

  // ---- register-resident weight fragments ----
  short8 F0[36], F1[64];
  {
    const short8* p0 = (const short8*)Wb0 + slot*36*64 + lane;
#pragma unroll
    for (int f=0; f<36; ++f) F0[f] = p0[f*64];
    const short8* p1 = (const short8*)Wb1 + slot*64*64 + lane;
#pragma unroll
    for (int f=0; f<64; ++f) F1[f] = p1[f*64];
  }
  float bia0[4], bia1[4];
#pragma unroll
  for (int nt=0; nt<4; ++nt){
    bia0[nt] = b0c[nt*256 + slot*16 + col16];
    bia1[nt] = b1c[nt*256 + slot*16 + col16];
  }
  const float wo = Wo[colg];
  const float bos = bo[0];

  // ---- init ----
  float c0[4], c1[4];
#pragma unroll
  for (int r=0; r<4; ++r){
    c0[r] = h0i[(rowbase + quad*4 + r)*HH + colg];
    c1[r] = c0[r];
  }
  for (int i = tid; i < 4096; i += 256){
    int m = i >> 8, k = i & 255;
    short v = f2bf(h0i[(rowbase+m)*HH + k]);
    int a = fragAddr(k,m);
    AH0[0][a] = v;        // h0(-1) = h0init
    AH1[a]    = v;        // h1(-1) = h0init (used at s==1)
  }
  {
    int m = tid >> 4, d = tid & 15;
    AX[0][fragAddr(d, m)] = f2bf(x[(rowbase+m)*TT*DD + d]);
    AX[0][fragAddr(16 + d, m)] = 0;
    AX[1][fragAddr(16 + d, m)] = 0;
  }
  __syncthreads();

  const f32x4 zero = {0.0f,0.0f,0.0f,0.0f};
  const int qd = tid & 3;
  const int cl = (tid >> 2) & 63;
  const int ka = (((c + 1) & 3) << 6) + cl;
  const int kb = (((c + 2) & 3) << 6) + cl;
  const int kc = (((c + 3) & 3) << 6) + cl;

  u64 pv1_prev = 0;   // my h1(s-2) packed, carried across the step boundary

#define CHKW(tv,dst,fl,TG) do{ u64 _t=(tv); \
    if(!(fl) && ((_t & TMASK64)==(TG))){ (dst)=_t & ~TMASK64; (fl)=true; } }while(0)

  for (int s=0; s<=TT; ++s){
    const bool doL0 = (s < TT);
    const bool doL1 = (s >= 1);
    const bool doH1x = (s >= 2);
    const int  p = s & 1;
    const unsigned T0 = (s>>1)&3;
    const unsigned w32_0 = ((T0&1)?0x4000u:0u) | ((T0&2)?0x40000000u:0u);
    const u64 tg0 = ((u64)w32_0<<32)|w32_0;
    const unsigned T1 = ((s-1)>>1)&3;
    const unsigned w32_1 = ((T1&1)?0x4000u:0u) | ((T1&2)?0x40000000u:0u);
    const u64 tg1 = ((u64)w32_1<<32)|w32_1;

    short* ax   = AX[p];   short* ah0   = AH0[p];
    short* ax_n = AX[p^1]; short* ah0_n = AH0[p^1];
    u64* rb0 = ring + (u64)(p*32+g)*2048;
    u64* rb1 = ring + (u64)(((s-1)&1)*32+g)*2048;
    u64* P0a = rb0 + (ka*4+qd)*2;
    u64* P0b = rb0 + (kb*4+qd)*2;
    u64* P0c = rb0 + (kc*4+qd)*2;
    u64* P1a = rb1 + (ka*4+qd)*2 + 1;
    u64* P1b = rb1 + (kb*4+qd)*2 + 1;
    u64* P1c = rb1 + (kc*4+qd)*2 + 1;

    RAW_BAR();  // B0: prev-step LDS writes visible (vmcnt untouched)

    // wave1: flush out(t=s-2) — oldest op in wave1's stream, retires early
    if (doH1x && tid >= 64 && tid < 80){
      int row = tid - 64;
      float v = outacc[p^1][row][0] + outacc[p^1][row][1]
              + outacc[p^1][row][2] + outacc[p^1][row][3];
      if (c == 0) v += bos;
      atomicAdd(&out[(rowbase + row)*TT + (s-2)], v);
    }

    // issue h1(s-2) polls: target published ~0.7P ago -> round-0 hit
    u64 e1a=0, e1b=0, e1c=0;
    if (doH1x){
      asm volatile(
        "global_load_dwordx2 %0, %3, off sc0 sc1\n\t"
        "global_load_dwordx2 %1, %4, off sc0 sc1\n\t"
        "global_load_dwordx2 %2, %5, off sc0 sc1"
        : "=&v"(e1a),"=&v"(e1b),"=&v"(e1c)
        : "v"(P1a),"v"(P1b),"v"(P1c) : "memory");
    }

    // x prefetch via asm, CLAMPED so the vmcnt stream is uniform for all doL0 steps
    float xf = 0.0f;
    if (doL0){
      int sx = (s+1 < TT) ? s+1 : TT-1;
      const float* xp = x + (rowbase+(tid>>4))*TT*DD + sx*DD + (tid&15);
      asm volatile("global_load_dword %0, %1, off" : "=&v"(xf) : "v"(xp) : "memory");
    }

    // ---- L0: 36 MFMA -> epi -> publish h0(s) -> own frags -> issue h0 polls ----
    u64 pv0 = 0;
    u64 e0a=0, e0b=0, e0c=0;
    if (doL0){
      f32x4 acc0[4];
#pragma unroll
      for (int nt=0; nt<4; ++nt) acc0[nt] = zero;
      {
        short8 a = *(const short8*)(ax + lane*8);
#pragma unroll
        for (int nt=0; nt<4; ++nt)
          acc0[nt] = __builtin_amdgcn_mfma_f32_16x16x32_bf16(a, F0[nt], acc0[nt], 0,0,0);
      }
#pragma unroll
      for (int ks=0; ks<8; ++ks){
        short8 a = *(const short8*)(ah0 + ks*512 + lane*8);
#pragma unroll
        for (int nt=0; nt<4; ++nt)
          acc0[nt] = __builtin_amdgcn_mfma_f32_16x16x32_bf16(a, F0[(ks+1)*4+nt], acc0[nt], 0,0,0);
      }
      float h0v[4];
#pragma unroll
      for (int r=0; r<4; ++r){
        float iv = sigm (acc0[0][r] + bia0[0]);
        float fv = sigm (acc0[1][r] + bia0[1]);
        float gv = tanhx(acc0[2][r] + bia0[2]);
        float ov = sigm (acc0[3][r] + bia0[3]);
        float cc = fv*c0[r] + iv*gv;
        c0[r] = cc;
        h0v[r] = ov * tanhx(cc);
      }
      pv0 = (((u64)cvtpk(h0v[2], h0v[3])) << 32) | cvtpk(h0v[0], h0v[1]);
      pub_store(rb0 + (colg*4+quad)*2, pv0 | tg0);
#pragma unroll
      for (int r=0; r<4; ++r)
        ah0_n[fragAddr(colg, quad*4 + r)] = (short)(pv0 >> (16*r));

      // issue h0(s) polls now (~0.27P): sample beats partner-store landing,
      // window to the tail check ~0.53P
      asm volatile(
        "global_load_dwordx2 %0, %3, off sc0 sc1\n\t"
        "global_load_dwordx2 %1, %4, off sc0 sc1\n\t"
        "global_load_dwordx2 %2, %5, off sc0 sc1"
        : "=&v"(e0a),"=&v"(e0b),"=&v"(e0c)
        : "v"(P0a),"v"(P0b),"v"(P0c) : "memory");
    }

    // ---- L1a: Wih1 x h0(s-1), uninterrupted ----
    f32x4 acc1[4];
#pragma unroll
    for (int nt=0; nt<4; ++nt) acc1[nt] = zero;
    if (doL1){
#pragma unroll
      for (int ks=0; ks<8; ++ks){
        short8 a = *(const short8*)(ah0 + ks*512 + lane*8);
#pragma unroll
        for (int nt=0; nt<4; ++nt)
          acc1[nt] = __builtin_amdgcn_mfma_f32_16x16x32_bf16(a, F1[ks*4+nt], acc1[nt], 0,0,0);
      }
    }

    // ---- check h1 polls; fill AH1 (partners + own pv1_prev) ----
    if (doH1x){
      if (doL0) asm volatile("s_waitcnt vmcnt(5)" ::: "memory"); // leaves xf,pubH0,h0p x3
      else      asm volatile("s_waitcnt vmcnt(0)" ::: "memory"); // s==TT
      __builtin_amdgcn_sched_barrier(0);   // rule-#18 fence
      u64 w1a=0,w1b=0,w1c=0;
      bool f1a=false,f1b=false,f1c=false;
      CHKW(e1a, w1a, f1a, tg1); CHKW(e1b, w1b, f1b, tg1); CHKW(e1c, w1c, f1c, tg1);
      while (!(f1a & f1b & f1c)){
        u64 t0,t1,t2;
        asm volatile(
          "global_load_dwordx2 %0, %3, off sc0 sc1\n\t"
          "global_load_dwordx2 %1, %4, off sc0 sc1\n\t"
          "global_load_dwordx2 %2, %5, off sc0 sc1\n\t"
          "s_waitcnt vmcnt(0)"
          : "=&v"(t0),"=&v"(t1),"=&v"(t2)
          : "v"(P1a),"v"(P1b),"v"(P1c) : "memory");
        __builtin_amdgcn_sched_barrier(0);
        CHKW(t0, w1a, f1a, tg1); CHKW(t1, w1b, f1b, tg1); CHKW(t2, w1c, f1c, tg1);
      }
      // own h1(s-2) from register; partners from polls
#pragma unroll
      for (int r=0; r<4; ++r)
        AH1[fragAddr(colg, quad*4 + r)] = (short)(pv1_prev >> (16*r));
      {
        short* sv = (short*)&w1a;
#pragma unroll
        for (int r=0; r<4; ++r) AH1[fragAddr(ka, qd*4 + r)] = sv[r];
        sv = (short*)&w1b;
#pragma unroll
        for (int r=0; r<4; ++r) AH1[fragAddr(kb, qd*4 + r)] = sv[r];
        sv = (short*)&w1c;
#pragma unroll
        for (int r=0; r<4; ++r) AH1[fragAddr(kc, qd*4 + r)] = sv[r];
      }
    }

    RAW_BAR();  // B1: AH1 ready (h0 polls + pub stores stay in flight)

    // ---- L1b: Whh1 x h1(s-2) -> epi -> publish h1(s-1) -> reduce ----
    u64 pv1 = 0;
    if (doL1){
#pragma unroll
      for (int ks=0; ks<8; ++ks){
        short8 a = *(const short8*)(AH1 + ks*512 + lane*8);
#pragma unroll
        for (int nt=0; nt<4; ++nt)
          acc1[nt] = __builtin_amdgcn_mfma_f32_16x16x32_bf16(a, F1[32+ks*4+nt], acc1[nt], 0,0,0);
      }
      float pr[4], h1v[4];
#pragma unroll
      for (int r=0; r<4; ++r){
        float iv = sigm (acc1[0][r] + bia1[0]);
        float fv = sigm (acc1[1][r] + bia1[1]);
        float gv = tanhx(acc1[2][r] + bia1[2]);
        float ov = sigm (acc1[3][r] + bia1[3]);
        float cc = fv*c1[r] + iv*gv;
        c1[r] = cc;
        float h = ov * tanhx(cc);
        h1v[r] = h;
        pr[r] = h * wo;
      }
      pv1 = (((u64)cvtpk(h1v[2], h1v[3])) << 32) | cvtpk(h1v[0], h1v[1]);
      if (doL0)
        pub_store(rb0 + (colg*4+quad)*2 + 1, pv1 | tg0);
#pragma unroll
      for (int m=1; m<16; m<<=1){
#pragma unroll
        for (int r=0; r<4; ++r) pr[r] += __shfl_xor(pr[r], m, 64);
      }
      if (col16 == 0){
#pragma unroll
        for (int r=0; r<4; ++r) outacc[p][quad*4 + r][w] = pr[r];
      }
    }

    // ---- tail: ONE gate -> AX stage + h0 check + partner frags ----
    if (doL0){
      if (doL1) asm volatile("s_waitcnt vmcnt(1)" ::: "memory");  // leaves pubH1 only
      else      asm volatile("s_waitcnt vmcnt(0)" ::: "memory");  // s==0
      __builtin_amdgcn_sched_barrier(0);   // rule-#18 fence
      if (s+1 < TT)
        ax_n[fragAddr(tid & 15, tid >> 4)] = f2bf(xf);

      u64 w0a=0,w0b=0,w0c=0;
      bool f0a=false,f0b=false,f0c=false;
      CHKW(e0a, w0a, f0a, tg0); CHKW(e0b, w0b, f0b, tg0); CHKW(e0c, w0c, f0c, tg0);
      while (!(f0a & f0b & f0c)){
        u64 t0,t1,t2;
        asm volatile(
          "global_load_dwordx2 %0, %3, off sc0 sc1\n\t"
          "global_load_dwordx2 %1, %4, off sc0 sc1\n\t"
          "global_load_dwordx2 %2, %5, off sc0 sc1\n\t"
          "s_waitcnt vmcnt(0)"
          : "=&v"(t0),"=&v"(t1),"=&v"(t2)
          : "v"(P0a),"v"(P0b),"v"(P0c) : "memory");
        __builtin_amdgcn_sched_barrier(0);
        CHKW(t0, w0a, f0a, tg0); CHKW(t1, w0b, f0b, tg0); CHKW(t2, w0c, f0c, tg0);
      }
      {
        short* sv = (short*)&w0a;
#pragma unroll
        for (int r=0; r<4; ++r) ah0_n[fragAddr(ka, qd*4 + r)] = sv[r];
        sv = (short*)&w0b;
#pragma unroll
        for (int r=0; r<4; ++r) ah0_n[fragAddr(kb, qd*4 + r)] = sv[r];
        sv = (short*)&w0c;
#pragma unroll
        for (int r=0; r<4; ++r) ah0_n[fragAddr(kc, qd*4 + r)] = sv[r];
      }
    }

    pv1_prev = pv1;
  }
#undef CHKW

  // ---- final flush: t = TT-1 lives in outacc[TT&1] ----
  RAW_BAR();
  if (tid < 16){
    const int pf = TT & 1;
    float v = outacc[pf][tid][0] + outacc[pf][tid][1]
            + outacc[pf][tid][2] + outacc[pf][tid][3];
    if (c == 0) v += bos;
    atomicAdd(&out[(rowbase + tid)*TT + (TT-1)], v);
  }
}

// ---------------- launch ----------------
extern "C" void kernel_launch(void* const* d_in, const int* in_sizes, int n_in,
                              void* d_out, int out_size, void* d_ws, size_t ws_size,
                              hipStream_t stream)
{
  const float* x    = (const float*)d_in[0];
  const float* xs   = (const float*)d_in[1];
  const float* Wih0 = (const float*)d_in[2];
  const float* Whh0 = (const float*)d_in[3];
  const float* bih0 = (const float*)d_in[4];
  const float* bhh0 = (const float*)d_in[5];
  const float* Wih1 = (const float*)d_in[6];
  const float* Whh1 = (const float*)d_in[7];
  const float* bih1 = (const float*)d_in[8];
  const float* bhh1 = (const float*)d_in[9];
  const float* Ws   = (const float*)d_in[10];
  const float* bs   = (const float*)d_in[11];
  const float* Wo   = (const float*)d_in[12];
  const float* bo   = (const float*)d_in[13];
  float* out = (float*)d_out;

  char* ws = (char*)d_ws;
  short*    Wb0   = (short*)(ws);                // 589824
  short*    Wb1   = (short*)(ws + 589824);       // 1048576 -> 1638400
  float*    h0i   = (float*)(ws + 1638400);      // 524288  -> 2162688
  float*    b0cp  = (float*)(ws + 2162688);      // 4096    -> 2166784
  float*    b1cp  = (float*)(ws + 2166784);      // 4096    -> 2170880
  u64*      ring  = (u64*)(ws + 2170880);        // 1048576 -> 3219456 (~3.22 MB)

  int nswz = 16*36*512 + 16*64*512;
  hipLaunchKernelGGL(prep_weights, dim3((nswz+255)/256), dim3(256), 0, stream,
                     Wih0, Whh0, Wih1, Whh1, Wb0, Wb1);
  hipLaunchKernelGGL(prep_h0, dim3(512), dim3(256), 0, stream, xs, Ws, bs, h0i);
  hipLaunchKernelGGL(prep_bias, dim3(8), dim3(256), 0, stream, bih0, bhh0, bih1, bhh1, b0cp, b1cp);
  hipLaunchKernelGGL(prep_zero, dim3(1024), dim3(256), 0, stream, out, ring);

  hipLaunchKernelGGL(lstm_fused, dim3(128), dim3(256), 0, stream,
                     Wb0, Wb1, h0i, b0cp, b1cp, x, Wo, bo, ring, out);
}